// Round 5
// baseline (10.579 us; speedup 1.0000x reference)
//
#include <hip/hip_runtime.h>

// Fused model kernel for MI355X (gfx950) — round 5: MFMA + shuffle epilogue.
//
// Reference collapse: the RNN carry is out = lin2(x_t) + b2 (independent of
// previous carry) -> only the last timestep matters. Read xs[r,S-1,b,:] only.
//
// MLP via v_mfma_f32_16x16x16_f16 computing transposed activations
// T = W * X^T + b. m89-verified layout identity: D (col=lane&15,
// row=4*(lane>>4)+reg) == B (col=lane&15, k=4*(lane>>4)+reg), so
// relu(D) feeds the next MFMA's B operand with zero data movement.
//
// Round-5 changes vs round 4:
//  * epilogue LDS round-trip removed -> 4 __shfl_xor moves (xor 16 and
//    xor 48); softmax groups split across two lanes per row (g=0 handles
//    [0:2]+[2:6], g=1 handles [6:10]); all stores 8B-aligned float2.
//  * per-tile pointer selects hoisted to lane-constant base + stride.
//  * no __shared__ at all.

#define RCELLS 5
#define TILES  2   // 16-row MFMA tiles per wave

typedef _Float16 half4 __attribute__((ext_vector_type(4)));
typedef float    f32x4 __attribute__((ext_vector_type(4)));

__global__ __launch_bounds__(256, 4) void fused_model_mfma(
    const float* __restrict__ x0,
    const float* __restrict__ xs,
    const float* __restrict__ rnn_w2,
    const float* __restrict__ rnn_b2,
    const float* __restrict__ w1,
    const float* __restrict__ b1,
    const float* __restrict__ w2,
    const float* __restrict__ b2,
    const float* __restrict__ w3,
    const float* __restrict__ b3,
    float* __restrict__ out,
    int B,
    long long sB2,      // S * B * 2   (stride between rnn cells in xs)
    long long lastOff)  // (S-1) * B * 2
{
    const int tid  = threadIdx.x;
    const int wid  = tid >> 6;
    const int lane = tid & 63;
    const int g    = lane >> 4;   // k-slice group (0..3)
    const int q    = lane & 15;   // row (A) / col (B,D) index
    const int base = blockIdx.x * (TILES * 16 * 4) + wid * (TILES * 16);

    // ---- persistent weight A-fragments: A[row=q][k=4g+i] ----
    half4 w1f, w2f, w3f;
    {
        float4 w = *reinterpret_cast<const float4*>(w1 + q * 16 + 4 * g);
        w1f[0] = (_Float16)w.x; w1f[1] = (_Float16)w.y;
        w1f[2] = (_Float16)w.z; w1f[3] = (_Float16)w.w;
        w = *reinterpret_cast<const float4*>(w2 + q * 16 + 4 * g);
        w2f[0] = (_Float16)w.x; w2f[1] = (_Float16)w.y;
        w2f[2] = (_Float16)w.z; w2f[3] = (_Float16)w.w;
        if (q < 10) {
            w = *reinterpret_cast<const float4*>(w3 + q * 16 + 4 * g);
            w3f[0] = (_Float16)w.x; w3f[1] = (_Float16)w.y;
            w3f[2] = (_Float16)w.z; w3f[3] = (_Float16)w.w;
        } else {
            w3f[0] = w3f[1] = w3f[2] = w3f[3] = (_Float16)0.0f;
        }
    }

    // ---- bias C-inits: C[row=4g+j][col=q] = bias[4g+j] ----
    f32x4 c1i, c2i, c3i;
    {
        float4 t = *reinterpret_cast<const float4*>(b1 + 4 * g);
        c1i[0] = t.x; c1i[1] = t.y; c1i[2] = t.z; c1i[3] = t.w;
        t = *reinterpret_cast<const float4*>(b2 + 4 * g);
        c2i[0] = t.x; c2i[1] = t.y; c2i[2] = t.z; c2i[3] = t.w;
        if (g < 2) {
            t = *reinterpret_cast<const float4*>(b3 + 4 * g);
            c3i[0] = t.x; c3i[1] = t.y; c3i[2] = t.z; c3i[3] = t.w;
        } else if (g == 2) {
            c3i[0] = b3[8]; c3i[1] = b3[9]; c3i[2] = 0.f; c3i[3] = 0.f;
        } else {
            c3i[0] = c3i[1] = c3i[2] = c3i[3] = 0.f;
        }
    }

    // ---- per-lane RNN affine coefficients for its two float2 loads ----
    // g0: feats 0-3  = x0[0:4]         (id, id)
    // g1: feats 4-7  = x0[4:6], cell0  (id, cell0)
    // g2: feats 8-11 = cell1, cell2
    // g3: feats12-15 = cell3, cell4
    float a00, a01, a10, a11, bx0, by0;   // transform of v0
    float c00, c01, c10, c11, bx1, by1;   // transform of v1
    {
        const int cell0 = (g == 2) ? 1 : (g == 3) ? 3 : -1;
        const int cell1 = (g == 1) ? 0 : (g == 2) ? 2 : (g == 3) ? 4 : -1;
        if (cell0 >= 0) {
            float4 w = *reinterpret_cast<const float4*>(rnn_w2 + cell0 * 4);
            float2 bb = *reinterpret_cast<const float2*>(rnn_b2 + cell0 * 2);
            a00 = w.x; a01 = w.y; a10 = w.z; a11 = w.w; bx0 = bb.x; by0 = bb.y;
        } else {
            a00 = 1.f; a01 = 0.f; a10 = 0.f; a11 = 1.f; bx0 = 0.f; by0 = 0.f;
        }
        if (cell1 >= 0) {
            float4 w = *reinterpret_cast<const float4*>(rnn_w2 + cell1 * 4);
            float2 bb = *reinterpret_cast<const float2*>(rnn_b2 + cell1 * 2);
            c00 = w.x; c01 = w.y; c10 = w.z; c11 = w.w; bx1 = bb.x; by1 = bb.y;
        } else {
            c00 = 1.f; c01 = 0.f; c10 = 0.f; c11 = 1.f; bx1 = 0.f; by1 = 0.f;
        }
    }

    // ---- lane-constant load bases/strides (row0 = this lane's t=0 row) ----
    const int row0 = min(base + q, B - 1);
    const float* p0b; const float* p1b; int st0, st1;
    if (g == 0) {
        p0b = x0 + (size_t)row0 * 6;     st0 = 6;
        p1b = x0 + (size_t)row0 * 6 + 2; st1 = 6;
    } else if (g == 1) {
        p0b = x0 + (size_t)row0 * 6 + 4;               st0 = 6;
        p1b = xs + lastOff + (size_t)row0 * 2;         st1 = 2;
    } else if (g == 2) {
        p0b = xs + lastOff + 1 * sB2 + (size_t)row0 * 2; st0 = 2;
        p1b = xs + lastOff + 2 * sB2 + (size_t)row0 * 2; st1 = 2;
    } else {
        p0b = xs + lastOff + 3 * sB2 + (size_t)row0 * 2; st0 = 2;
        p1b = xs + lastOff + 4 * sB2 + (size_t)row0 * 2; st1 = 2;
    }

    // ---- per-tile: build B-fragment, 3 chained MFMAs, shuffle epilogue ----
#pragma unroll
    for (int t = 0; t < TILES; ++t) {
        const float2 v0 = *reinterpret_cast<const float2*>(p0b + (size_t)(t * 16) * st0);
        const float2 v1 = *reinterpret_cast<const float2*>(p1b + (size_t)(t * 16) * st1);

        const float f0 = fmaf(a00, v0.x, fmaf(a01, v0.y, bx0));
        const float f1 = fmaf(a10, v0.x, fmaf(a11, v0.y, by0));
        const float f2 = fmaf(c00, v1.x, fmaf(c01, v1.y, bx1));
        const float f3 = fmaf(c10, v1.x, fmaf(c11, v1.y, by1));

        half4 xbv;
        xbv[0] = (_Float16)f0; xbv[1] = (_Float16)f1;
        xbv[2] = (_Float16)f2; xbv[3] = (_Float16)f3;

        f32x4 d1 = __builtin_amdgcn_mfma_f32_16x16x16f16(w1f, xbv, c1i, 0, 0, 0);
        half4 h1v;
        h1v[0] = (_Float16)fmaxf(d1[0], 0.f); h1v[1] = (_Float16)fmaxf(d1[1], 0.f);
        h1v[2] = (_Float16)fmaxf(d1[2], 0.f); h1v[3] = (_Float16)fmaxf(d1[3], 0.f);

        f32x4 d2 = __builtin_amdgcn_mfma_f32_16x16x16f16(w2f, h1v, c2i, 0, 0, 0);
        half4 h2v;
        h2v[0] = (_Float16)fmaxf(d2[0], 0.f); h2v[1] = (_Float16)fmaxf(d2[1], 0.f);
        h2v[2] = (_Float16)fmaxf(d2[2], 0.f); h2v[3] = (_Float16)fmaxf(d2[3], 0.f);

        f32x4 d3 = __builtin_amdgcn_mfma_f32_16x16x16f16(w3f, h2v, c3i, 0, 0, 0);

        // D[feat=4g+j][batch=q] in d3[j].
        // Row q's logits: feats0-3 @ lane q; 4-7 @ lane q+16; 8,9 @ lane q+32.
        // Lane q      needs feats 4,5 -> shfl_xor 16 of d3[0],d3[1]
        // Lane q+16   needs feats 8,9 -> shfl_xor 48 of d3[0],d3[1]
        const float e0 = __shfl_xor(d3[0], 16, 64);
        const float e1 = __shfl_xor(d3[1], 16, 64);
        const float f8 = __shfl_xor(d3[0], 48, 64);
        const float f9 = __shfl_xor(d3[1], 48, 64);

        const int row = base + t * 16 + q;
        if (g == 0 && row < B) {
            // softmax [0:2] from d3[0],d3[1]; softmax [2:6] from d3[2],d3[3],e0,e1
            float m = fmaxf(d3[0], d3[1]);
            float u0 = __expf(d3[0] - m), u1 = __expf(d3[1] - m);
            float inv = 1.0f / (u0 + u1);
            float m2 = fmaxf(fmaxf(d3[2], d3[3]), fmaxf(e0, e1));
            float u2 = __expf(d3[2] - m2), u3 = __expf(d3[3] - m2);
            float u4 = __expf(e0 - m2),   u5 = __expf(e1 - m2);
            float inv2 = 1.0f / (u2 + u3 + u4 + u5);
            float2* po = reinterpret_cast<float2*>(out + (size_t)row * 10);
            po[0] = make_float2(u0 * inv,  u1 * inv);
            po[1] = make_float2(u2 * inv2, u3 * inv2);
            po[2] = make_float2(u4 * inv2, u5 * inv2);
        } else if (g == 1 && row < B) {
            // softmax [6:10] from d3[2],d3[3] (feats 6,7) and f8,f9 (feats 8,9)
            float m = fmaxf(fmaxf(d3[2], d3[3]), fmaxf(f8, f9));
            float u6 = __expf(d3[2] - m), u7 = __expf(d3[3] - m);
            float u8 = __expf(f8 - m),   u9 = __expf(f9 - m);
            float inv = 1.0f / (u6 + u7 + u8 + u9);
            float2* po = reinterpret_cast<float2*>(out + (size_t)row * 10);
            po[3] = make_float2(u6 * inv, u7 * inv);
            po[4] = make_float2(u8 * inv, u9 * inv);
        }
    }
}

extern "C" void kernel_launch(void* const* d_in, const int* in_sizes, int n_in,
                              void* d_out, int out_size, void* d_ws, size_t ws_size,
                              hipStream_t stream) {
    const float* x0     = (const float*)d_in[0];
    const float* xs     = (const float*)d_in[1];
    // d_in[2] = rnn_w1, d_in[3] = rnn_b1 -- dead code in the reference (DCE'd)
    const float* rnn_w2 = (const float*)d_in[4];
    const float* rnn_b2 = (const float*)d_in[5];
    const float* w1     = (const float*)d_in[6];
    const float* b1     = (const float*)d_in[7];
    const float* w2     = (const float*)d_in[8];
    const float* b2     = (const float*)d_in[9];
    const float* w3     = (const float*)d_in[10];
    const float* b3     = (const float*)d_in[11];

    const int B = in_sizes[0] / 6;                    // x0 is [B, 6]
    const int S = in_sizes[1] / (RCELLS * 2 * B);     // xs is [R, S, B, 2]
    const long long sB2     = (long long)S * B * 2;
    const long long lastOff = (long long)(S - 1) * B * 2;

    const int rowsPerBlock = TILES * 16 * 4;          // 128
    const int grid = (B + rowsPerBlock - 1) / rowsPerBlock;
    fused_model_mfma<<<grid, 256, 0, stream>>>(
        x0, xs, rnn_w2, rnn_b2, w1, b1, w2, b2, w3, b3,
        (float*)d_out, B, sB2, lastOff);
}